// Round 7
// baseline (283.494 us; speedup 1.0000x reference)
//
#include <hip/hip_runtime.h>

#define HID 256
typedef unsigned short ushort_t;
typedef unsigned int uint_t;
typedef __attribute__((ext_vector_type(8))) short short8;
typedef __attribute__((ext_vector_type(4))) float f32x4;
typedef __attribute__((ext_vector_type(4))) unsigned short us4;
typedef __attribute__((ext_vector_type(8))) unsigned short us8;

__device__ __forceinline__ ushort_t f2b(float f) {
    uint_t u = __float_as_uint(f);
    u = u + 0x7fffu + ((u >> 16) & 1u);   // RNE
    return (ushort_t)(u >> 16);
}

// ---------------- degree count (edge-only, 1 edge/thread) ----------------
__global__ __launch_bounds__(256) void k_count(const int* __restrict__ dst,
                                               int* __restrict__ cnt, int E) {
    int i = blockIdx.x * 256 + threadIdx.x;
    if (i < E) atomicAdd(&cnt[dst[i]], 1);
}

// ---------------- graph counts via binary search (batch sorted, no atomics) ----------
__global__ __launch_bounds__(256) void k_gcnt_search(const int* __restrict__ batch,
                                                     int* __restrict__ gcnt, int n, int G) {
    int g = blockIdx.x * 256 + threadIdx.x;
    if (g >= G) return;
    int lo = 0, hi = n;
    while (lo < hi) { int mid = (lo + hi) >> 1; if (batch[mid] < g) lo = mid + 1; else hi = mid; }
    int lb = lo;
    hi = n;
    while (lo < hi) { int mid = (lo + hi) >> 1; if (batch[mid] < g + 1) lo = mid + 1; else hi = mid; }
    gcnt[g] = lo - lb;
}

// ---------------- block sums + dis (fused) ----------------
__global__ __launch_bounds__(256) void k_bsum_dis(const int* __restrict__ cnt,
                                                  int* __restrict__ bsum,
                                                  float* __restrict__ dis, int n) {
    __shared__ int s[256];
    int t = threadIdx.x;
    int i = blockIdx.x * 256 + t;
    int c = (i < n) ? cnt[i] : 0;
    if (i < n) dis[i] = rsqrtf((float)(c + 1));
    s[t] = c;
    __syncthreads();
#pragma unroll
    for (int d = 128; d > 0; d >>= 1) {
        if (t < d) s[t] += s[t + d];
        __syncthreads();
    }
    if (t == 0) bsum[blockIdx.x] = s[0];
}

// exclusive scan of block sums (nb <= 256)
__global__ __launch_bounds__(256) void k_scan_bsum(const int* __restrict__ bsum,
                                                   int* __restrict__ boff, int nb) {
    __shared__ int s[256];
    int t = threadIdx.x;
    int v = (t < nb) ? bsum[t] : 0;
    s[t] = v;
    __syncthreads();
#pragma unroll
    for (int d = 1; d < 256; d <<= 1) {
        int u = (t >= d) ? s[t - d] : 0;
        __syncthreads();
        s[t] += u;
        __syncthreads();
    }
    if (t < nb) boff[t] = s[t] - v;
}

// per-chunk exclusive scan + block offset; writes off AND working copy woff
__global__ __launch_bounds__(256) void k_scan_fin(const int* __restrict__ cnt,
                                                  const int* __restrict__ boff,
                                                  int* __restrict__ off,
                                                  int* __restrict__ woff, int n, int E) {
    __shared__ int s[256];
    int t = threadIdx.x;
    int i = blockIdx.x * 256 + t;
    int v = (i < n) ? cnt[i] : 0;
    s[t] = v;
    __syncthreads();
#pragma unroll
    for (int d = 1; d < 256; d <<= 1) {
        int u = (t >= d) ? s[t - d] : 0;
        __syncthreads();
        s[t] += u;
        __syncthreads();
    }
    if (i < n) {
        int o = boff[blockIdx.x] + s[t] - v;
        off[i] = o;
        woff[i] = o;
    }
    if (blockIdx.x == 0 && t == 0) off[n] = E;
}

// ---------------- CSR fill (by dst); woff doubles as position counter ----------------
__global__ __launch_bounds__(256) void k_fill(const int* __restrict__ src,
                                              const int* __restrict__ dst,
                                              int* __restrict__ woff,
                                              int* __restrict__ csr, int E) {
    int i = blockIdx.x * 256 + threadIdx.x;
    if (i < E) {
        int pos = atomicAdd(&woff[dst[i]], 1);
        csr[pos] = src[i];
    }
}

// ---------------- cast: Xg (grouped [K/32][n][32]) = bf16(dis[row] * x) ----------------
__global__ void k_cast(const float* __restrict__ x, const float* __restrict__ dis,
                       ushort_t* __restrict__ xg, int total8, int rshift, int n) {
    int i = blockIdx.x * blockDim.x + threadIdx.x;
    if (i >= total8) return;
    int r = i >> rshift;                  // row
    int j = i & ((1 << rshift) - 1);      // which us8 within the row
    float dv = dis[r];
    const float4* p = (const float4*)(x + (size_t)i * 8);
    float4 v0 = p[0], v1 = p[1];
    us8 o;
    o[0] = f2b(v0.x * dv); o[1] = f2b(v0.y * dv); o[2] = f2b(v0.z * dv); o[3] = f2b(v0.w * dv);
    o[4] = f2b(v1.x * dv); o[5] = f2b(v1.y * dv); o[6] = f2b(v1.z * dv); o[7] = f2b(v1.w * dv);
    size_t dst = (size_t)(j >> 2) * ((size_t)n * 32) + (size_t)r * 32 + (size_t)(j & 3) * 8;
    *(us8*)(xg + dst) = o;
}

// ---------------- W -> transposed, bf16, K-panel-blocked, PRE-SWIZZLED ----------------
__global__ void k_prep_wt(const float* __restrict__ W, ushort_t* __restrict__ Wt) {
    int kg = blockIdx.x;        // k row of W
    int c = threadIdx.x;        // 0..255 column
    float v = W[(size_t)kg * HID + c];
    int p = kg >> 6;
    int k = kg & 63;
    int byte_ = c * 128 + k * 2;
    int slot = byte_ >> 4;
    int sw = (slot & ~7) | ((slot ^ c) & 7);
    size_t dst_byte = (size_t)p * 32768 + ((size_t)sw << 4) + (byte_ & 15);
    Wt[dst_byte >> 1] = f2b(v);
}

// ---------------- grouped aggregation ----------------
// Yg: grouped [NG][n][32] bf16. Z: row-major [n][NG*32] bf16.
// group = blockIdx.x % NG  (round-robin blockIdx->XCD pins each group to one XCD's L2).
// Quarter-wave (16 lanes = 4 parities x 4 lanes x 16B) per node.
// Unroll-4 with up-front index loads: one round of csr latency + one round of gather
// latency covers 4 edges per parity (16 edges/node in flight).
#define ACC8(r)                                                            \
    a0 += __uint_as_float((r).x << 16); a1 += __uint_as_float((r).x & 0xffff0000u); \
    a2 += __uint_as_float((r).y << 16); a3 += __uint_as_float((r).y & 0xffff0000u); \
    a4 += __uint_as_float((r).z << 16); a5 += __uint_as_float((r).z & 0xffff0000u); \
    a6 += __uint_as_float((r).w << 16); a7 += __uint_as_float((r).w & 0xffff0000u);

template <int NG>
__global__ __launch_bounds__(256) void k_agg_g(const ushort_t* __restrict__ Yg,
                                               ushort_t* __restrict__ Z,
                                               const int* __restrict__ off,
                                               const int* __restrict__ csr,
                                               const float* __restrict__ dis, int n) {
    const int LOG = (NG == 8) ? 3 : 2;
    const int g = blockIdx.x & (NG - 1);
    const int chunk = blockIdx.x >> LOG;
    const int q = threadIdx.x >> 4;       // quarter index within block (16 nodes/block)
    const int l16 = threadIdx.x & 15;
    const int v = chunk * 16 + q;
    if (v >= n) return;
    const int par = l16 >> 2;             // 0..3 edge parity
    const int sub = l16 & 3;              // 0..3 -> 8 channels (16B) each
    const uint4* Yb = (const uint4*)(Yg + (size_t)g * ((size_t)n * 32));  // 4 uint4/row
    uint4 self;
    if (par == 0) self = Yb[(uint_t)v * 4u + sub];   // early issue, used in epilogue
    float a0 = 0.f, a1 = 0.f, a2 = 0.f, a3 = 0.f, a4 = 0.f, a5 = 0.f, a6 = 0.f, a7 = 0.f;
    int e = off[v] + par;
    const int end = off[v + 1];
    while (e + 12 < end) {
        int s0 = csr[e], s1 = csr[e + 4], s2 = csr[e + 8], s3 = csr[e + 12];
        uint4 r0 = Yb[(uint_t)s0 * 4u + sub];
        uint4 r1 = Yb[(uint_t)s1 * 4u + sub];
        uint4 r2 = Yb[(uint_t)s2 * 4u + sub];
        uint4 r3 = Yb[(uint_t)s3 * 4u + sub];
        ACC8(r0); ACC8(r1); ACC8(r2); ACC8(r3);
        e += 16;
    }
    while (e < end) {
        int s0 = csr[e];
        uint4 r0 = Yb[(uint_t)s0 * 4u + sub];
        ACC8(r0);
        e += 4;
    }
    // reduce the 4 parities (stays within the 16-lane quarter)
    a0 += __shfl_xor(a0, 4, 64); a1 += __shfl_xor(a1, 4, 64);
    a2 += __shfl_xor(a2, 4, 64); a3 += __shfl_xor(a3, 4, 64);
    a4 += __shfl_xor(a4, 4, 64); a5 += __shfl_xor(a5, 4, 64);
    a6 += __shfl_xor(a6, 4, 64); a7 += __shfl_xor(a7, 4, 64);
    a0 += __shfl_xor(a0, 8, 64); a1 += __shfl_xor(a1, 8, 64);
    a2 += __shfl_xor(a2, 8, 64); a3 += __shfl_xor(a3, 8, 64);
    a4 += __shfl_xor(a4, 8, 64); a5 += __shfl_xor(a5, 8, 64);
    a6 += __shfl_xor(a6, 8, 64); a7 += __shfl_xor(a7, 8, 64);
    if (par == 0) {
        ACC8(self);   // self loop
        float dv = dis[v];
        us8 o;
        o[0] = f2b(a0 * dv); o[1] = f2b(a1 * dv); o[2] = f2b(a2 * dv); o[3] = f2b(a3 * dv);
        o[4] = f2b(a4 * dv); o[5] = f2b(a5 * dv); o[6] = f2b(a6 * dv); o[7] = f2b(a7 * dv);
        *(us8*)(Z + (size_t)v * (NG * 32) + g * 32 + sub * 8) = o;
    }
}

// ---------------- MFMA GEMM: Yout[row][c] = bf16( post( A[row]·W[:,c] + bias[c] ) ) ----
// post = relu, then (SCALE ? *dis[row] : identity). OUTG: write grouped [8][M][32].
template <int K, bool SCALE, bool OUTG>
__global__ __launch_bounds__(512) void k_gemm_mfma(const ushort_t* __restrict__ A,
                                                   const ushort_t* __restrict__ Wt,
                                                   const float* __restrict__ dis,
                                                   const float* __restrict__ bias,
                                                   ushort_t* __restrict__ Yout, int M) {
    __shared__ char lds[49152];
    char* As = lds;            // 128 rows x 64 k bf16, swizzled: 16384 B
    char* Bs = lds + 16384;    // 256 cols x 64 k bf16, swizzled: 32768 B
    const int tid = threadIdx.x;
    const int lane = tid & 63;
    const int w = tid >> 6;
    const int wm = w & 1;
    const int wn = w >> 1;
    const int row0 = blockIdx.x * 128;

    f32x4 acc[4][4];
#pragma unroll
    for (int i = 0; i < 4; ++i)
#pragma unroll
        for (int j = 0; j < 4; ++j) acc[i][j] = (f32x4){0.f, 0.f, 0.f, 0.f};

    for (int k0 = 0; k0 < K; k0 += 64) {
#pragma unroll
        for (int q = 0; q < 2; ++q) {
            int s = q * 512 + tid;
            int r = s >> 3;
            int kseg = (s & 7) ^ (r & 7);
            int row = row0 + r;
            if (row >= M) row = 0;
            const ushort_t* g = A + (size_t)row * K + k0 + kseg * 8;
            __builtin_amdgcn_global_load_lds((const uint_t*)g,
                                             (uint_t*)(As + q * 8192 + w * 1024), 16, 0, 0);
        }
        const ushort_t* gp = Wt + (size_t)(k0 >> 6) * (256 * 64);
#pragma unroll
        for (int q = 0; q < 4; ++q) {
            int s = q * 512 + tid;
            __builtin_amdgcn_global_load_lds((const uint_t*)(gp + (size_t)s * 8),
                                             (uint_t*)(Bs + q * 8192 + w * 1024), 16, 0, 0);
        }
        __syncthreads();
#pragma unroll
        for (int k32 = 0; k32 < 2; ++k32) {
            const int ksl = k32 * 4 + (lane >> 4);
            short8 wf[4], xf[4];
#pragma unroll
            for (int nn = 0; nn < 4; ++nn) {
                int col = wn * 64 + nn * 16 + (lane & 15);
                int slot = col * 8 + (ksl ^ (col & 7));
                wf[nn] = *(const short8*)(Bs + slot * 16);
            }
#pragma unroll
            for (int m = 0; m < 4; ++m) {
                int row = wm * 64 + m * 16 + (lane & 15);
                int slot = row * 8 + (ksl ^ (row & 7));
                xf[m] = *(const short8*)(As + slot * 16);
            }
#pragma unroll
            for (int nn = 0; nn < 4; ++nn)
#pragma unroll
                for (int m = 0; m < 4; ++m)
                    acc[nn][m] = __builtin_amdgcn_mfma_f32_16x16x32_bf16(wf[nn], xf[m],
                                                                         acc[nn][m], 0, 0, 0);
        }
        __syncthreads();
    }
    const int m_lo = lane & 15, c_hi = lane >> 4;
#pragma unroll
    for (int m = 0; m < 4; ++m) {
        int row = row0 + wm * 64 + m * 16 + m_lo;
        if (row < M) {
            float dv = SCALE ? dis[row] : 1.f;
#pragma unroll
            for (int nn = 0; nn < 4; ++nn) {
                int c0 = wn * 64 + nn * 16 + c_hi * 4;
                float4 bb = *(const float4*)(bias + c0);
                us4 o;
                o[0] = f2b(fmaxf(acc[nn][m][0] + bb.x, 0.f) * dv);
                o[1] = f2b(fmaxf(acc[nn][m][1] + bb.y, 0.f) * dv);
                o[2] = f2b(fmaxf(acc[nn][m][2] + bb.z, 0.f) * dv);
                o[3] = f2b(fmaxf(acc[nn][m][3] + bb.w, 0.f) * dv);
                size_t dst = OUTG
                    ? ((size_t)(c0 >> 5) * ((size_t)M * 32) + (size_t)row * 32 + (c0 & 31))
                    : ((size_t)row * HID + c0);
                *(us4*)(Yout + dst) = o;
            }
        }
    }
}

// ---------------- pooling ----------------
__global__ __launch_bounds__(256) void k_pool(const ushort_t* __restrict__ H,
                                              const int* __restrict__ batch,
                                              float* __restrict__ out, int n) {
    int c = threadIdx.x;
    int n0 = blockIdx.x * 128;
    if (n0 >= n) return;
    int nEnd = min(n0 + 128, n);
    int g = batch[n0];
    float sum = 0.f;
    for (int i = n0; i < nEnd; ++i) {
        int gi = batch[i];
        if (gi != g) {
            atomicAdd(&out[(size_t)g * HID + c], sum);
            sum = 0.f;
            g = gi;
        }
        sum += __uint_as_float(((uint_t)H[(size_t)i * HID + c]) << 16);
    }
    atomicAdd(&out[(size_t)g * HID + c], sum);
}

__global__ void k_div(float* __restrict__ out, const int* __restrict__ gcnt, int G) {
    int g = blockIdx.x;
    int c = threadIdx.x;
    float d = (float)max(gcnt[g], 1);
    out[(size_t)g * HID + c] /= d;
}

extern "C" void kernel_launch(void* const* d_in, const int* in_sizes, int n_in,
                              void* d_out, int out_size, void* d_ws, size_t ws_size,
                              hipStream_t stream) {
    const float* x = (const float*)d_in[0];
    const float* W1 = (const float*)d_in[1];
    const float* b1 = (const float*)d_in[2];
    const float* W2 = (const float*)d_in[3];
    const float* b2 = (const float*)d_in[4];
    const int* ei = (const int*)d_in[5];
    const int* batch = (const int*)d_in[6];
    float* out = (float*)d_out;

    const int N = in_sizes[6];        // 50000
    const int E = in_sizes[5] / 2;    // 800000
    const int K1 = in_sizes[0] / N;   // 128
    const int G = out_size / HID;     // 500
    (void)n_in; (void)ws_size;

    char* w = (char*)d_ws;
    int* cnt = (int*)(w + 0);                       // 50000 i32
    float* dis = (float*)(w + 200704);              // 50000 f32
    int* off = (int*)(w + 401408);                  // 50001 i32
    int* woff = (int*)(w + 602112);                 // 50000 i32 (working copy)
    int* csr = (int*)(w + 802816);                  // 800000 i32
    int* gcnt = (int*)(w + 4003840);                // 500 i32
    int* bsum = (int*)(w + 4005888);                // 256 i32
    int* boff = (int*)(w + 4006912);                // 256 i32
    ushort_t* Wt1 = (ushort_t*)(w + 4007936);       // 128*256 bf16 pre-swizzled
    ushort_t* Wt2 = (ushort_t*)(w + 4073472);       // 256*256 bf16
    ushort_t* Xg = (ushort_t*)(w + 4204544);        // grouped [4][N][32] bf16 (dis*x)
    ushort_t* Z1 = (ushort_t*)(w + 17004544);       // [N][128] bf16
    ushort_t* H1g = (ushort_t*)(w + 29804544);      // grouped [8][N][32] bf16
    ushort_t* Z2 = (ushort_t*)(w + 55404544);       // [N][256] bf16
    ushort_t* H2 = (ushort_t*)(w + 4204544);        // [N][256] bf16 (aliases Xg+Z1, both dead)

    hipMemsetAsync(cnt, 0, (size_t)N * sizeof(int), stream);
    hipMemsetAsync(out, 0, (size_t)out_size * sizeof(float), stream);

    const int nb = (N + 255) / 256;   // 196
    const int eb = (E + 255) / 256;   // 3125
    k_count<<<eb, 256, 0, stream>>>(ei + E, cnt, E);
    k_gcnt_search<<<(G + 255) / 256, 256, 0, stream>>>(batch, gcnt, N, G);
    k_bsum_dis<<<nb, 256, 0, stream>>>(cnt, bsum, dis, N);
    k_scan_bsum<<<1, 256, 0, stream>>>(bsum, boff, nb);
    k_scan_fin<<<nb, 256, 0, stream>>>(cnt, boff, off, woff, N, E);
    k_fill<<<eb, 256, 0, stream>>>(ei, ei + E, woff, csr, E);

    int rshift = 31 - __builtin_clz((unsigned)(K1 / 8));   // log2(K1/8) = 4
    k_cast<<<(N * K1 / 8 + 255) / 256, 256, 0, stream>>>(x, dis, Xg, N * K1 / 8, rshift, N);
    k_prep_wt<<<K1, 256, 0, stream>>>(W1, Wt1);
    k_prep_wt<<<HID, 256, 0, stream>>>(W2, Wt2);

    int gblk = (N + 127) / 128;
    const int chunks = (N + 15) / 16;  // 3125
    // layer 1: grouped aggregate (4 groups x 32ch), then GEMM (fused bias+relu+dis, grouped out)
    k_agg_g<4><<<4 * chunks, 256, 0, stream>>>(Xg, Z1, off, csr, dis, N);
    k_gemm_mfma<128, true, true><<<gblk, 512, 0, stream>>>(Z1, Wt1, dis, b1, H1g, N);
    // layer 2: grouped aggregate (8 groups x 32ch), then GEMM (fused bias+relu, row-major out)
    k_agg_g<8><<<8 * chunks, 256, 0, stream>>>(H1g, Z2, off, csr, dis, N);
    k_gemm_mfma<256, false, false><<<gblk, 512, 0, stream>>>(Z2, Wt2, dis, b2, H2, N);

    k_pool<<<(N + 127) / 128, 256, 0, stream>>>(H2, batch, out, N);
    k_div<<<G, HID, 0, stream>>>(out, gcnt, G);
}

// Round 8
// 227.785 us; speedup vs baseline: 1.2446x; 1.2446x over previous
//
#include <hip/hip_runtime.h>

#define HID 256
#define SLOTS 32
#define OVCAP 16384
typedef unsigned short ushort_t;
typedef unsigned int uint_t;
typedef __attribute__((ext_vector_type(8))) short short8;
typedef __attribute__((ext_vector_type(4))) float f32x4;
typedef __attribute__((ext_vector_type(4))) unsigned short us4;
typedef __attribute__((ext_vector_type(8))) unsigned short us8;

__device__ __forceinline__ ushort_t f2b(float f) {
    uint_t u = __float_as_uint(f);
    u = u + 0x7fffu + ((u >> 16) & 1u);   // RNE
    return (ushort_t)(u >> 16);
}

// ---------------- fused degree-count + fixed-slot CSR fill (ONE edge pass) -----------
__global__ __launch_bounds__(256) void k_countfill(const int* __restrict__ src,
                                                   const int* __restrict__ dst,
                                                   int* __restrict__ cnt,
                                                   int* __restrict__ csr2,
                                                   int* __restrict__ ovn,
                                                   int2* __restrict__ ov, int E) {
    int i = blockIdx.x * 256 + threadIdx.x;
    if (i >= E) return;
    int d = dst[i], s = src[i];
    int c = atomicAdd(&cnt[d], 1);
    if (c < SLOTS) {
        csr2[d * SLOTS + c] = s;
    } else {
        int p = atomicAdd(ovn, 1);
        if (p < OVCAP) ov[p] = make_int2(d, s);
    }
}

// ---------------- fused: W1 prep | W2 prep | cast x -> Xg (dis inline from cnt) ------
// prep: W -> transposed bf16, K-panel-blocked, pre-swizzled (panel 32768B; byte
// c*128+k*2; 16B slot low3 ^= c&7). cast: Xg grouped [K1/32][n][32] = bf16(dis*x).
__global__ __launch_bounds__(256) void k_castprep(const float* __restrict__ x,
                                                  const int* __restrict__ cnt,
                                                  ushort_t* __restrict__ xg,
                                                  const float* __restrict__ W1,
                                                  ushort_t* __restrict__ Wt1,
                                                  const float* __restrict__ W2,
                                                  ushort_t* __restrict__ Wt2,
                                                  int n, int rshift, int p1b, int p2b) {
    int bid = blockIdx.x;
    if (bid < p1b + p2b) {
        const float* W = (bid < p1b) ? W1 : W2;
        ushort_t* Wt = (bid < p1b) ? Wt1 : Wt2;
        int kg = (bid < p1b) ? bid : bid - p1b;
        int c = threadIdx.x;
        float v = W[(size_t)kg * HID + c];
        int p = kg >> 6;
        int k = kg & 63;
        int byte_ = c * 128 + k * 2;
        int slot = byte_ >> 4;
        int sw = (slot & ~7) | ((slot ^ c) & 7);
        size_t dst_byte = (size_t)p * 32768 + ((size_t)sw << 4) + (byte_ & 15);
        Wt[dst_byte >> 1] = f2b(v);
        return;
    }
    int i = (bid - p1b - p2b) * 256 + threadIdx.x;
    int total8 = n << rshift;
    if (i >= total8) return;
    int r = i >> rshift;
    int j = i & ((1 << rshift) - 1);
    float dv = rsqrtf((float)(cnt[r] + 1));
    const float4* p = (const float4*)(x + (size_t)i * 8);
    float4 v0 = p[0], v1 = p[1];
    us8 o;
    o[0] = f2b(v0.x * dv); o[1] = f2b(v0.y * dv); o[2] = f2b(v0.z * dv); o[3] = f2b(v0.w * dv);
    o[4] = f2b(v1.x * dv); o[5] = f2b(v1.y * dv); o[6] = f2b(v1.z * dv); o[7] = f2b(v1.w * dv);
    size_t dst = (size_t)(j >> 2) * ((size_t)n * 32) + (size_t)r * 32 + (size_t)(j & 3) * 8;
    *(us8*)(xg + dst) = o;
}

// ---------------- grouped aggregation over fixed-slot CSR ----------------
// Yg: grouped [NG][n][32] bf16. Z: row-major [n][NG*32] bf16.
// group = blockIdx.x % NG (round-robin blockIdx->XCD pins each group slice in L2).
// Quarter-wave (16 lanes = 4 parities x 4 subs x 16B) per node. dis inline from cnt.
#define ACC8(r)                                                            \
    a0 += __uint_as_float((r).x << 16); a1 += __uint_as_float((r).x & 0xffff0000u); \
    a2 += __uint_as_float((r).y << 16); a3 += __uint_as_float((r).y & 0xffff0000u); \
    a4 += __uint_as_float((r).z << 16); a5 += __uint_as_float((r).z & 0xffff0000u); \
    a6 += __uint_as_float((r).w << 16); a7 += __uint_as_float((r).w & 0xffff0000u);

template <int NG>
__global__ __launch_bounds__(256) void k_agg_g(const ushort_t* __restrict__ Yg,
                                               ushort_t* __restrict__ Z,
                                               const int* __restrict__ cnt,
                                               const int* __restrict__ csr2,
                                               const int* __restrict__ ovn,
                                               const int2* __restrict__ ov, int n) {
    const int LOG = (NG == 8) ? 3 : 2;
    const int g = blockIdx.x & (NG - 1);
    const int chunk = blockIdx.x >> LOG;
    const int q = threadIdx.x >> 4;
    const int l16 = threadIdx.x & 15;
    const int v = chunk * 16 + q;
    if (v >= n) return;
    const int par = l16 >> 2;
    const int sub = l16 & 3;
    const uint4* Yb = (const uint4*)(Yg + (size_t)g * ((size_t)n * 32));
    uint4 self;
    if (par == 0) self = Yb[(uint_t)v * 4u + sub];
    const int deg = cnt[v];
    const int lim = min(deg, SLOTS);
    const int* row = csr2 + v * SLOTS;
    float a0 = 0.f, a1 = 0.f, a2 = 0.f, a3 = 0.f, a4 = 0.f, a5 = 0.f, a6 = 0.f, a7 = 0.f;
    int e = par;
    while (e + 4 < lim) {
        int s0 = row[e], s1 = row[e + 4];
        uint4 r0 = Yb[(uint_t)s0 * 4u + sub];
        uint4 r1 = Yb[(uint_t)s1 * 4u + sub];
        ACC8(r0); ACC8(r1);
        e += 8;
    }
    if (e < lim) {
        int s0 = row[e];
        uint4 r0 = Yb[(uint_t)s0 * 4u + sub];
        ACC8(r0);
    }
    if (deg > SLOTS) {   // rare (~7 nodes): scan tiny overflow list
        int m = min(*ovn, OVCAP);
        for (int i2 = par; i2 < m; i2 += 4) {
            int2 p = ov[i2];
            if (p.x == v) { uint4 r = Yb[(uint_t)p.y * 4u + sub]; ACC8(r); }
        }
    }
    a0 += __shfl_xor(a0, 4, 64); a1 += __shfl_xor(a1, 4, 64);
    a2 += __shfl_xor(a2, 4, 64); a3 += __shfl_xor(a3, 4, 64);
    a4 += __shfl_xor(a4, 4, 64); a5 += __shfl_xor(a5, 4, 64);
    a6 += __shfl_xor(a6, 4, 64); a7 += __shfl_xor(a7, 4, 64);
    a0 += __shfl_xor(a0, 8, 64); a1 += __shfl_xor(a1, 8, 64);
    a2 += __shfl_xor(a2, 8, 64); a3 += __shfl_xor(a3, 8, 64);
    a4 += __shfl_xor(a4, 8, 64); a5 += __shfl_xor(a5, 8, 64);
    a6 += __shfl_xor(a6, 8, 64); a7 += __shfl_xor(a7, 8, 64);
    if (par == 0) {
        ACC8(self);
        float dv = rsqrtf((float)(deg + 1));
        us8 o;
        o[0] = f2b(a0 * dv); o[1] = f2b(a1 * dv); o[2] = f2b(a2 * dv); o[3] = f2b(a3 * dv);
        o[4] = f2b(a4 * dv); o[5] = f2b(a5 * dv); o[6] = f2b(a6 * dv); o[7] = f2b(a7 * dv);
        *(us8*)(Z + (size_t)v * (NG * 32) + g * 32 + sub * 8) = o;
    }
}

// ---------------- MFMA GEMM: Yout[row][c] = bf16( post( A[row]·W[:,c] + bias[c] ) ) ----
// post = relu, then (SCALE ? *rsqrt(cnt[row]+1) : identity). OUTG: grouped [8][M][32].
template <int K, bool SCALE, bool OUTG>
__global__ __launch_bounds__(512) void k_gemm_mfma(const ushort_t* __restrict__ A,
                                                   const ushort_t* __restrict__ Wt,
                                                   const int* __restrict__ cnt,
                                                   const float* __restrict__ bias,
                                                   ushort_t* __restrict__ Yout, int M) {
    __shared__ char lds[49152];
    char* As = lds;            // 128 rows x 64 k bf16, swizzled: 16384 B
    char* Bs = lds + 16384;    // 256 cols x 64 k bf16, swizzled: 32768 B
    const int tid = threadIdx.x;
    const int lane = tid & 63;
    const int w = tid >> 6;
    const int wm = w & 1;
    const int wn = w >> 1;
    const int row0 = blockIdx.x * 128;

    f32x4 acc[4][4];
#pragma unroll
    for (int i = 0; i < 4; ++i)
#pragma unroll
        for (int j = 0; j < 4; ++j) acc[i][j] = (f32x4){0.f, 0.f, 0.f, 0.f};

    for (int k0 = 0; k0 < K; k0 += 64) {
#pragma unroll
        for (int q = 0; q < 2; ++q) {
            int s = q * 512 + tid;
            int r = s >> 3;
            int kseg = (s & 7) ^ (r & 7);
            int row = row0 + r;
            if (row >= M) row = 0;
            const ushort_t* g = A + (size_t)row * K + k0 + kseg * 8;
            __builtin_amdgcn_global_load_lds((const uint_t*)g,
                                             (uint_t*)(As + q * 8192 + w * 1024), 16, 0, 0);
        }
        const ushort_t* gp = Wt + (size_t)(k0 >> 6) * (256 * 64);
#pragma unroll
        for (int q = 0; q < 4; ++q) {
            int s = q * 512 + tid;
            __builtin_amdgcn_global_load_lds((const uint_t*)(gp + (size_t)s * 8),
                                             (uint_t*)(Bs + q * 8192 + w * 1024), 16, 0, 0);
        }
        __syncthreads();
#pragma unroll
        for (int k32 = 0; k32 < 2; ++k32) {
            const int ksl = k32 * 4 + (lane >> 4);
            short8 wf[4], xf[4];
#pragma unroll
            for (int nn = 0; nn < 4; ++nn) {
                int col = wn * 64 + nn * 16 + (lane & 15);
                int slot = col * 8 + (ksl ^ (col & 7));
                wf[nn] = *(const short8*)(Bs + slot * 16);
            }
#pragma unroll
            for (int m = 0; m < 4; ++m) {
                int row = wm * 64 + m * 16 + (lane & 15);
                int slot = row * 8 + (ksl ^ (row & 7));
                xf[m] = *(const short8*)(As + slot * 16);
            }
#pragma unroll
            for (int nn = 0; nn < 4; ++nn)
#pragma unroll
                for (int m = 0; m < 4; ++m)
                    acc[nn][m] = __builtin_amdgcn_mfma_f32_16x16x32_bf16(wf[nn], xf[m],
                                                                         acc[nn][m], 0, 0, 0);
        }
        __syncthreads();
    }
    const int m_lo = lane & 15, c_hi = lane >> 4;
#pragma unroll
    for (int m = 0; m < 4; ++m) {
        int row = row0 + wm * 64 + m * 16 + m_lo;
        if (row < M) {
            float dv = SCALE ? rsqrtf((float)(cnt[row] + 1)) : 1.f;
#pragma unroll
            for (int nn = 0; nn < 4; ++nn) {
                int c0 = wn * 64 + nn * 16 + c_hi * 4;
                float4 bb = *(const float4*)(bias + c0);
                us4 o;
                o[0] = f2b(fmaxf(acc[nn][m][0] + bb.x, 0.f) * dv);
                o[1] = f2b(fmaxf(acc[nn][m][1] + bb.y, 0.f) * dv);
                o[2] = f2b(fmaxf(acc[nn][m][2] + bb.z, 0.f) * dv);
                o[3] = f2b(fmaxf(acc[nn][m][3] + bb.w, 0.f) * dv);
                size_t dst = OUTG
                    ? ((size_t)(c0 >> 5) * ((size_t)M * 32) + (size_t)row * 32 + (c0 & 31))
                    : ((size_t)row * HID + c0);
                *(us4*)(Yout + dst) = o;
            }
        }
    }
}

// ---------------- pooling: one block per graph, atomic-free, fused divide ------------
// batch sorted -> graph g occupies rows [lower_bound(g), lower_bound(g+1)).
__global__ __launch_bounds__(256) void k_pool2(const ushort_t* __restrict__ H,
                                               const int* __restrict__ batch,
                                               float* __restrict__ out, int n) {
    __shared__ int se[2];
    int g = blockIdx.x;
    if (threadIdx.x < 2) {
        int tgt = g + (int)threadIdx.x;
        int lo = 0, hi = n;
        while (lo < hi) { int mid = (lo + hi) >> 1; if (batch[mid] < tgt) lo = mid + 1; else hi = mid; }
        se[threadIdx.x] = lo;
    }
    __syncthreads();
    int s = se[0], e = se[1];
    int c = threadIdx.x;
    float sum = 0.f;
    for (int i = s; i < e; ++i)
        sum += __uint_as_float(((uint_t)H[(size_t)i * HID + c]) << 16);
    out[(size_t)g * HID + c] = sum / (float)max(e - s, 1);
}

extern "C" void kernel_launch(void* const* d_in, const int* in_sizes, int n_in,
                              void* d_out, int out_size, void* d_ws, size_t ws_size,
                              hipStream_t stream) {
    const float* x = (const float*)d_in[0];
    const float* W1 = (const float*)d_in[1];
    const float* b1 = (const float*)d_in[2];
    const float* W2 = (const float*)d_in[3];
    const float* b2 = (const float*)d_in[4];
    const int* ei = (const int*)d_in[5];
    const int* batch = (const int*)d_in[6];
    float* out = (float*)d_out;

    const int N = in_sizes[6];        // 50000
    const int E = in_sizes[5] / 2;    // 800000
    const int K1 = in_sizes[0] / N;   // 128
    const int G = out_size / HID;     // 500
    (void)n_in; (void)ws_size;

    char* w = (char*)d_ws;
    int* cnt = (int*)(w + 0);                       // 50000 i32
    int* ovn = (int*)(w + 200000);                  // 1 i32 (zeroed together with cnt)
    int2* ov = (int2*)(w + 200064);                 // 16384 int2
    int* csr2 = (int*)(w + 331136);                 // 50000*32 i32 = 6.4 MB
    ushort_t* Wt1 = (ushort_t*)(w + 6731136);       // 128*256 bf16 pre-swizzled
    ushort_t* Wt2 = (ushort_t*)(w + 6796672);       // 256*256 bf16
    ushort_t* Xg = (ushort_t*)(w + 6927744);        // grouped [4][N][32] bf16 (dis*x)
    ushort_t* Z1 = (ushort_t*)(w + 19727744);       // [N][128] bf16
    ushort_t* H1g = (ushort_t*)(w + 32527744);      // grouped [8][N][32] bf16
    ushort_t* Z2 = (ushort_t*)(w + 6927744);        // [N][256] bf16 (overlays Xg+Z1, dead)
    ushort_t* H2 = (ushort_t*)(w + 32527744);       // [N][256] bf16 (overlays H1g, dead)

    // zero cnt + ovn in one memset
    hipMemsetAsync(cnt, 0, 200064, stream);

    const int eb = (E + 255) / 256;                       // 3125
    k_countfill<<<eb, 256, 0, stream>>>(ei, ei + E, cnt, csr2, ovn, ov, E);

    int rshift = 31 - __builtin_clz((unsigned)(K1 / 8));  // 4
    int castb = (N * K1 / 8 + 255) / 256;                 // 3125
    k_castprep<<<K1 + HID + castb, 256, 0, stream>>>(x, cnt, Xg, W1, Wt1, W2, Wt2,
                                                     N, rshift, K1, HID);

    int gblk = (N + 127) / 128;
    const int chunks = (N + 15) / 16;  // 3125
    // layer 1: grouped aggregate (4 groups x 32ch), then GEMM (fused bias+relu+dis)
    k_agg_g<4><<<4 * chunks, 256, 0, stream>>>(Xg, Z1, cnt, csr2, ovn, ov, N);
    k_gemm_mfma<128, true, true><<<gblk, 512, 0, stream>>>(Z1, Wt1, cnt, b1, H1g, N);
    // layer 2: grouped aggregate (8 groups x 32ch), then GEMM (fused bias+relu)
    k_agg_g<8><<<8 * chunks, 256, 0, stream>>>(H1g, Z2, cnt, csr2, ovn, ov, N);
    k_gemm_mfma<256, false, false><<<gblk, 512, 0, stream>>>(Z2, Wt2, cnt, b2, H2, N);

    k_pool2<<<G, 256, 0, stream>>>(H2, batch, out, N);
}

// Round 9
// 227.042 us; speedup vs baseline: 1.2486x; 1.0033x over previous
//
#include <hip/hip_runtime.h>

#define HID 256
#define SLOTS 32
#define OVCAP 16384
#define CS 16   // cnt stride (ints) -> one counter per 64B line
typedef unsigned short ushort_t;
typedef unsigned int uint_t;
typedef __attribute__((ext_vector_type(8))) short short8;
typedef __attribute__((ext_vector_type(4))) float f32x4;
typedef __attribute__((ext_vector_type(4))) unsigned short us4;
typedef __attribute__((ext_vector_type(8))) unsigned short us8;

__device__ __forceinline__ ushort_t f2b(float f) {
    uint_t u = __float_as_uint(f);
    u = u + 0x7fffu + ((u >> 16) & 1u);   // RNE
    return (ushort_t)(u >> 16);
}

// ---------------- fused degree-count + fixed-slot CSR fill (ONE edge pass) -----------
// cnt padded to 1 counter / 64B line: same-line atomic serialization was the wall.
__global__ __launch_bounds__(256) void k_countfill(const int* __restrict__ src,
                                                   const int* __restrict__ dst,
                                                   int* __restrict__ cnt,
                                                   int* __restrict__ csr2,
                                                   int* __restrict__ ovn,
                                                   int2* __restrict__ ov, int E) {
    int i = blockIdx.x * 256 + threadIdx.x;
    if (i >= E) return;
    int d = dst[i], s = src[i];
    int c = atomicAdd(&cnt[d * CS], 1);
    if (c < SLOTS) {
        csr2[d * SLOTS + c] = s;
    } else {
        int p = atomicAdd(ovn, 1);
        if (p < OVCAP) ov[p] = make_int2(d, s);
    }
}

// ---------------- fused: W1 prep | W2 prep | cast x -> Xg (dis inline from cnt) ------
__global__ __launch_bounds__(256) void k_castprep(const float* __restrict__ x,
                                                  const int* __restrict__ cnt,
                                                  ushort_t* __restrict__ xg,
                                                  const float* __restrict__ W1,
                                                  ushort_t* __restrict__ Wt1,
                                                  const float* __restrict__ W2,
                                                  ushort_t* __restrict__ Wt2,
                                                  int n, int rshift, int p1b, int p2b) {
    int bid = blockIdx.x;
    if (bid < p1b + p2b) {
        const float* W = (bid < p1b) ? W1 : W2;
        ushort_t* Wt = (bid < p1b) ? Wt1 : Wt2;
        int kg = (bid < p1b) ? bid : bid - p1b;
        int c = threadIdx.x;
        float v = W[(size_t)kg * HID + c];
        int p = kg >> 6;
        int k = kg & 63;
        int byte_ = c * 128 + k * 2;
        int slot = byte_ >> 4;
        int sw = (slot & ~7) | ((slot ^ c) & 7);
        size_t dst_byte = (size_t)p * 32768 + ((size_t)sw << 4) + (byte_ & 15);
        Wt[dst_byte >> 1] = f2b(v);
        return;
    }
    int i = (bid - p1b - p2b) * 256 + threadIdx.x;
    int total8 = n << rshift;
    if (i >= total8) return;
    int r = i >> rshift;
    int j = i & ((1 << rshift) - 1);
    float dv = rsqrtf((float)(cnt[r * CS] + 1));
    const float4* p = (const float4*)(x + (size_t)i * 8);
    float4 v0 = p[0], v1 = p[1];
    us8 o;
    o[0] = f2b(v0.x * dv); o[1] = f2b(v0.y * dv); o[2] = f2b(v0.z * dv); o[3] = f2b(v0.w * dv);
    o[4] = f2b(v1.x * dv); o[5] = f2b(v1.y * dv); o[6] = f2b(v1.z * dv); o[7] = f2b(v1.w * dv);
    size_t dst = (size_t)(j >> 2) * ((size_t)n * 32) + (size_t)r * 32 + (size_t)(j & 3) * 8;
    *(us8*)(xg + dst) = o;
}

// ---------------- grouped aggregation over fixed-slot CSR ----------------
#define ACC8(r)                                                            \
    a0 += __uint_as_float((r).x << 16); a1 += __uint_as_float((r).x & 0xffff0000u); \
    a2 += __uint_as_float((r).y << 16); a3 += __uint_as_float((r).y & 0xffff0000u); \
    a4 += __uint_as_float((r).z << 16); a5 += __uint_as_float((r).z & 0xffff0000u); \
    a6 += __uint_as_float((r).w << 16); a7 += __uint_as_float((r).w & 0xffff0000u);

template <int NG>
__global__ __launch_bounds__(256) void k_agg_g(const ushort_t* __restrict__ Yg,
                                               ushort_t* __restrict__ Z,
                                               const int* __restrict__ cnt,
                                               const int* __restrict__ csr2,
                                               const int* __restrict__ ovn,
                                               const int2* __restrict__ ov, int n) {
    const int LOG = (NG == 8) ? 3 : 2;
    const int g = blockIdx.x & (NG - 1);
    const int chunk = blockIdx.x >> LOG;
    const int q = threadIdx.x >> 4;
    const int l16 = threadIdx.x & 15;
    const int v = chunk * 16 + q;
    if (v >= n) return;
    const int par = l16 >> 2;
    const int sub = l16 & 3;
    const uint4* Yb = (const uint4*)(Yg + (size_t)g * ((size_t)n * 32));
    uint4 self;
    if (par == 0) self = Yb[(uint_t)v * 4u + sub];
    const int deg = cnt[v * CS];
    const int lim = min(deg, SLOTS);
    const int* row = csr2 + v * SLOTS;
    float a0 = 0.f, a1 = 0.f, a2 = 0.f, a3 = 0.f, a4 = 0.f, a5 = 0.f, a6 = 0.f, a7 = 0.f;
    int e = par;
    while (e + 4 < lim) {
        int s0 = row[e], s1 = row[e + 4];
        uint4 r0 = Yb[(uint_t)s0 * 4u + sub];
        uint4 r1 = Yb[(uint_t)s1 * 4u + sub];
        ACC8(r0); ACC8(r1);
        e += 8;
    }
    if (e < lim) {
        int s0 = row[e];
        uint4 r0 = Yb[(uint_t)s0 * 4u + sub];
        ACC8(r0);
    }
    if (deg > SLOTS) {   // rare: scan tiny overflow list
        int m = min(*ovn, OVCAP);
        for (int i2 = par; i2 < m; i2 += 4) {
            int2 p = ov[i2];
            if (p.x == v) { uint4 r = Yb[(uint_t)p.y * 4u + sub]; ACC8(r); }
        }
    }
    a0 += __shfl_xor(a0, 4, 64); a1 += __shfl_xor(a1, 4, 64);
    a2 += __shfl_xor(a2, 4, 64); a3 += __shfl_xor(a3, 4, 64);
    a4 += __shfl_xor(a4, 4, 64); a5 += __shfl_xor(a5, 4, 64);
    a6 += __shfl_xor(a6, 4, 64); a7 += __shfl_xor(a7, 4, 64);
    a0 += __shfl_xor(a0, 8, 64); a1 += __shfl_xor(a1, 8, 64);
    a2 += __shfl_xor(a2, 8, 64); a3 += __shfl_xor(a3, 8, 64);
    a4 += __shfl_xor(a4, 8, 64); a5 += __shfl_xor(a5, 8, 64);
    a6 += __shfl_xor(a6, 8, 64); a7 += __shfl_xor(a7, 8, 64);
    if (par == 0) {
        ACC8(self);
        float dv = rsqrtf((float)(deg + 1));
        us8 o;
        o[0] = f2b(a0 * dv); o[1] = f2b(a1 * dv); o[2] = f2b(a2 * dv); o[3] = f2b(a3 * dv);
        o[4] = f2b(a4 * dv); o[5] = f2b(a5 * dv); o[6] = f2b(a6 * dv); o[7] = f2b(a7 * dv);
        *(us8*)(Z + (size_t)v * (NG * 32) + g * 32 + sub * 8) = o;
    }
}

// ---------------- MFMA GEMM: Yout[row][c] = bf16( post( A[row]·W[:,c] + bias[c] ) ) ----
template <int K, bool SCALE, bool OUTG>
__global__ __launch_bounds__(512) void k_gemm_mfma(const ushort_t* __restrict__ A,
                                                   const ushort_t* __restrict__ Wt,
                                                   const int* __restrict__ cnt,
                                                   const float* __restrict__ bias,
                                                   ushort_t* __restrict__ Yout, int M) {
    __shared__ char lds[49152];
    char* As = lds;            // 128 rows x 64 k bf16, swizzled: 16384 B
    char* Bs = lds + 16384;    // 256 cols x 64 k bf16, swizzled: 32768 B
    const int tid = threadIdx.x;
    const int lane = tid & 63;
    const int w = tid >> 6;
    const int wm = w & 1;
    const int wn = w >> 1;
    const int row0 = blockIdx.x * 128;

    f32x4 acc[4][4];
#pragma unroll
    for (int i = 0; i < 4; ++i)
#pragma unroll
        for (int j = 0; j < 4; ++j) acc[i][j] = (f32x4){0.f, 0.f, 0.f, 0.f};

    for (int k0 = 0; k0 < K; k0 += 64) {
#pragma unroll
        for (int q = 0; q < 2; ++q) {
            int s = q * 512 + tid;
            int r = s >> 3;
            int kseg = (s & 7) ^ (r & 7);
            int row = row0 + r;
            if (row >= M) row = 0;
            const ushort_t* g = A + (size_t)row * K + k0 + kseg * 8;
            __builtin_amdgcn_global_load_lds((const uint_t*)g,
                                             (uint_t*)(As + q * 8192 + w * 1024), 16, 0, 0);
        }
        const ushort_t* gp = Wt + (size_t)(k0 >> 6) * (256 * 64);
#pragma unroll
        for (int q = 0; q < 4; ++q) {
            int s = q * 512 + tid;
            __builtin_amdgcn_global_load_lds((const uint_t*)(gp + (size_t)s * 8),
                                             (uint_t*)(Bs + q * 8192 + w * 1024), 16, 0, 0);
        }
        __syncthreads();
#pragma unroll
        for (int k32 = 0; k32 < 2; ++k32) {
            const int ksl = k32 * 4 + (lane >> 4);
            short8 wf[4], xf[4];
#pragma unroll
            for (int nn = 0; nn < 4; ++nn) {
                int col = wn * 64 + nn * 16 + (lane & 15);
                int slot = col * 8 + (ksl ^ (col & 7));
                wf[nn] = *(const short8*)(Bs + slot * 16);
            }
#pragma unroll
            for (int m = 0; m < 4; ++m) {
                int row = wm * 64 + m * 16 + (lane & 15);
                int slot = row * 8 + (ksl ^ (row & 7));
                xf[m] = *(const short8*)(As + slot * 16);
            }
#pragma unroll
            for (int nn = 0; nn < 4; ++nn)
#pragma unroll
                for (int m = 0; m < 4; ++m)
                    acc[nn][m] = __builtin_amdgcn_mfma_f32_16x16x32_bf16(wf[nn], xf[m],
                                                                         acc[nn][m], 0, 0, 0);
        }
        __syncthreads();
    }
    const int m_lo = lane & 15, c_hi = lane >> 4;
#pragma unroll
    for (int m = 0; m < 4; ++m) {
        int row = row0 + wm * 64 + m * 16 + m_lo;
        if (row < M) {
            float dv = SCALE ? rsqrtf((float)(cnt[row * CS] + 1)) : 1.f;
#pragma unroll
            for (int nn = 0; nn < 4; ++nn) {
                int c0 = wn * 64 + nn * 16 + c_hi * 4;
                float4 bb = *(const float4*)(bias + c0);
                us4 o;
                o[0] = f2b(fmaxf(acc[nn][m][0] + bb.x, 0.f) * dv);
                o[1] = f2b(fmaxf(acc[nn][m][1] + bb.y, 0.f) * dv);
                o[2] = f2b(fmaxf(acc[nn][m][2] + bb.z, 0.f) * dv);
                o[3] = f2b(fmaxf(acc[nn][m][3] + bb.w, 0.f) * dv);
                size_t dst = OUTG
                    ? ((size_t)(c0 >> 5) * ((size_t)M * 32) + (size_t)row * 32 + (c0 & 31))
                    : ((size_t)row * HID + c0);
                *(us4*)(Yout + dst) = o;
            }
        }
    }
}

// ---------------- pooling: one block per graph, atomic-free, fused divide ------------
__global__ __launch_bounds__(256) void k_pool2(const ushort_t* __restrict__ H,
                                               const int* __restrict__ batch,
                                               float* __restrict__ out, int n) {
    __shared__ int se[2];
    int g = blockIdx.x;
    if (threadIdx.x < 2) {
        int tgt = g + (int)threadIdx.x;
        int lo = 0, hi = n;
        while (lo < hi) { int mid = (lo + hi) >> 1; if (batch[mid] < tgt) lo = mid + 1; else hi = mid; }
        se[threadIdx.x] = lo;
    }
    __syncthreads();
    int s = se[0], e = se[1];
    int c = threadIdx.x;
    float sum = 0.f;
    for (int i = s; i < e; ++i)
        sum += __uint_as_float(((uint_t)H[(size_t)i * HID + c]) << 16);
    out[(size_t)g * HID + c] = sum / (float)max(e - s, 1);
}

extern "C" void kernel_launch(void* const* d_in, const int* in_sizes, int n_in,
                              void* d_out, int out_size, void* d_ws, size_t ws_size,
                              hipStream_t stream) {
    const float* x = (const float*)d_in[0];
    const float* W1 = (const float*)d_in[1];
    const float* b1 = (const float*)d_in[2];
    const float* W2 = (const float*)d_in[3];
    const float* b2 = (const float*)d_in[4];
    const int* ei = (const int*)d_in[5];
    const int* batch = (const int*)d_in[6];
    float* out = (float*)d_out;

    const int N = in_sizes[6];        // 50000
    const int E = in_sizes[5] / 2;    // 800000
    const int K1 = in_sizes[0] / N;   // 128
    const int G = out_size / HID;     // 500
    (void)n_in; (void)ws_size;

    char* w = (char*)d_ws;
    int* cnt = (int*)(w + 0);                       // 50000 x 64B-strided i32 = 3.2 MB
    int* ovn = (int*)(w + 3200000);                 // 1 i32 (zeroed with cnt)
    int2* ov = (int2*)(w + 3200064);                // 16384 int2
    int* csr2 = (int*)(w + 3331136);                // 50000*32 i32 = 6.4 MB
    ushort_t* Wt1 = (ushort_t*)(w + 9731136);       // 128*256 bf16 pre-swizzled
    ushort_t* Wt2 = (ushort_t*)(w + 9796672);       // 256*256 bf16
    ushort_t* Xg = (ushort_t*)(w + 9927744);        // grouped [4][N][32] bf16 (dis*x)
    ushort_t* Z1 = (ushort_t*)(w + 22727744);       // [N][128] bf16
    ushort_t* H1g = (ushort_t*)(w + 35527744);      // grouped [8][N][32] bf16
    ushort_t* Z2 = (ushort_t*)(w + 9927744);        // [N][256] bf16 (overlays Xg+Z1, dead)
    ushort_t* H2 = (ushort_t*)(w + 35527744);       // [N][256] bf16 (overlays H1g, dead)

    // zero cnt (padded) + ovn in one memset
    hipMemsetAsync(cnt, 0, 3200064, stream);

    const int eb = (E + 255) / 256;                       // 3125
    k_countfill<<<eb, 256, 0, stream>>>(ei, ei + E, cnt, csr2, ovn, ov, E);

    int rshift = 31 - __builtin_clz((unsigned)(K1 / 8));  // 4
    int castb = (N * K1 / 8 + 255) / 256;                 // 3125
    k_castprep<<<K1 + HID + castb, 256, 0, stream>>>(x, cnt, Xg, W1, Wt1, W2, Wt2,
                                                     N, rshift, K1, HID);

    int gblk = (N + 127) / 128;
    const int chunks = (N + 15) / 16;  // 3125
    // layer 1: grouped aggregate (4 groups x 32ch), then GEMM (fused bias+relu+dis)
    k_agg_g<4><<<4 * chunks, 256, 0, stream>>>(Xg, Z1, cnt, csr2, ovn, ov, N);
    k_gemm_mfma<128, true, true><<<gblk, 512, 0, stream>>>(Z1, Wt1, cnt, b1, H1g, N);
    // layer 2: grouped aggregate (8 groups x 32ch), then GEMM (fused bias+relu)
    k_agg_g<8><<<8 * chunks, 256, 0, stream>>>(H1g, Z2, cnt, csr2, ovn, ov, N);
    k_gemm_mfma<256, false, false><<<gblk, 512, 0, stream>>>(Z2, Wt2, cnt, b2, H2, N);

    k_pool2<<<G, 256, 0, stream>>>(H2, batch, out, N);
}